// Round 9
// baseline (246.709 us; speedup 1.0000x reference)
//
#include <hip/hip_runtime.h>
#include <math.h>

#define kB 2
#define kS 2048
#define kD 1024
#define kH 16
#define kM (kB * kS)     /* 4096 */

#define kC 0.180336880f   /* 0.125 * log2(e) — folded into Wq/bq at prep time */

typedef unsigned short u16;
typedef unsigned int u32;
typedef unsigned long long u64;
typedef short s16x8 __attribute__((ext_vector_type(8)));     /* bf16 MFMA frag */
typedef float f32x4 __attribute__((ext_vector_type(4)));     /* MFMA acc */

/* raw v_exp_f32 (no OCML denormal guard — inputs bounded, masked after) */
#if __has_builtin(__builtin_amdgcn_exp2f)
#define EXP2(x) __builtin_amdgcn_exp2f(x)
#else
#define EXP2(x) exp2f(x)
#endif

/* fp32 -> bf16 round-to-nearest-even (scalar) */
__device__ __forceinline__ u16 f2bf(float f) {
    u32 u = __float_as_uint(f);
    u += 0x7FFFu + ((u >> 16) & 1u);
    return (u16)(u >> 16);
}

/* pack two fp32 -> two bf16 in one u32 via v_cvt_pk_bf16_f32 (1 VALU op) */
__device__ __forceinline__ u32 cvt_pk_bf16(float lo, float hi) {
    u32 r;
    asm("v_cvt_pk_bf16_f32 %0, %1, %2" : "=v"(r) : "v"(lo), "v"(hi));
    return r;
}

typedef __attribute__((address_space(1))) void as1_void;
typedef __attribute__((address_space(3))) void as3_void;
__device__ __forceinline__ void async_copy16(const void* g, void* l) {
    __builtin_amdgcn_global_load_lds((as1_void*)(unsigned long long)g,
                                     (as3_void*)(unsigned)(unsigned long long)l,
                                     16, 0, 0);
}

/* ---------------- fused prep: bf16 converts + mask permute ---------------- */
__global__ __launch_bounds__(256) void prep(
        const float* __restrict__ xq, const float* __restrict__ xk, const float* __restrict__ xv,
        const float* __restrict__ Wq, const float* __restrict__ Wk,
        const float* __restrict__ Wv, const float* __restrict__ Wo,
        const int* __restrict__ msk,
        u16* __restrict__ xqb, u16* __restrict__ xkb, u16* __restrict__ xvb,
        u16* __restrict__ wqb, u16* __restrict__ wkb, u16* __restrict__ wvb,
        u16* __restrict__ wob, u64* __restrict__ prepM) {
    const int bid = blockIdx.x;
    const int tid = threadIdx.x;
    if (bid < 16384) {
        const float* in;
        u16* out;
        int i;
        float sc = 1.0f;
        if (bid < 12288) {
            const int z = bid >> 12;
            in = z == 0 ? xq : (z == 1 ? xk : xv);
            out = z == 0 ? xqb : (z == 1 ? xkb : xvb);
            i = (bid & 4095) * 256 + tid;
        } else {
            const int z = (bid - 12288) >> 10;
            in = z == 0 ? Wq : (z == 1 ? Wk : (z == 2 ? Wv : Wo));
            out = z == 0 ? wqb : (z == 1 ? wkb : (z == 2 ? wvb : wob));
            if (z == 0) sc = kC;            /* fold softmax scale into Wq */
            i = ((bid - 12288) & 1023) * 256 + tid;
        }
        const float4 v = ((const float4*)in)[i];
        ushort4 o;
        o.x = f2bf(v.x * sc); o.y = f2bf(v.y * sc);
        o.z = f2bf(v.z * sc); o.w = f2bf(v.w * sc);
        ((ushort4*)out)[i] = o;
    } else {
        const int wid = (bid - 16384) * 4 + (tid >> 6);  /* 0..8191 */
        const int lane = tid & 63;
        const int kt = wid & 31, qb = (wid >> 5) & 127, b = wid >> 12;
        const int q = qb * 16 + (lane & 15);
        const int kbase = kt * 64 + ((lane >> 4) << 2);
        const int* mrow = msk + ((size_t)b * kS + q) * kS;
        u64 keep = 0;
#pragma unroll
        for (int c = 0; c < 4; ++c) {
            const int4 m4 = *(const int4*)(mrow + kbase + c * 16);
            const int mv[4] = {m4.x, m4.y, m4.z, m4.w};
#pragma unroll
            for (int r = 0; r < 4; ++r) {
                const u64 bl = __ballot(mv[r] != 0);
                if (lane == c * 4 + r) keep = bl;
            }
        }
        if (lane < 16)
            prepM[(((size_t)b * 128 + qb) * 32 + kt) * 16 + lane] = keep;
    }
}

/* ---------------- bf16 GEMM: C = A[M,K] @ W[N,K]^T + bias*bscale ----------
 * TILEM x TILEN tile, BK=32 double-buffered, one barrier per K-step, shared
 * LDS from kernel scope, TILEN=64 (R7), T1 XCD swizzle (R6, GEMMs only).
 * MODE 0: bf16 out; MODE 2: f32 out; MODE 3: V^T out [(b*H+h)*64+d][s].
 */
template <int MODE, int TILEM, int TILEN>
__device__ __forceinline__ void gemm_bt_body(const u16* __restrict__ A,
                                             const u16* __restrict__ W,
                                             const float* __restrict__ bias,
                                             void* __restrict__ Cp,
                                             const float bscale,
                                             u16* __restrict__ AsM,
                                             u16* __restrict__ BsM,
                                             const int bxi, const int byi) {
    constexpr int FM = TILEM / 32;           /* m-frags per wave */
    constexpr int FN = TILEN / 32;           /* n-frags per wave */
    u16* As0 = AsM;            u16* As1 = AsM + TILEM * 32;
    u16* Bs0 = BsM;            u16* Bs1 = BsM + TILEN * 32;
    const int tid = threadIdx.x;
    const int wave = tid >> 6, lane = tid & 63;
    const int l15 = lane & 15, quad = lane >> 4;
    const int wr = wave >> 1, wc = wave & 1;
    const int m0 = (MODE == 3 ? bxi : byi) * TILEM;
    const int n0 = (MODE == 3 ? byi : bxi) * TILEN;

    /* staging: lane λ covers row λ>>2 of a 16-row block, slot λ&3; the slot
     * holds global chunk c = ((λ&3) - ((λ>>3)&3)) & 3 (rotation inverse) */
    const int srow = lane >> 2;                          /* 0..15 */
    const int schk = ((lane & 3) - ((lane >> 3) & 3)) & 3;
    const u16* gA = A + (size_t)(m0 + (TILEM / 4) * wave + srow) * kD + schk * 8;
    const u16* gB = W + (size_t)(n0 + (TILEN / 4) * wave + srow) * kD + schk * 8;

    f32x4 acc[FM][FN];
#pragma unroll
    for (int i = 0; i < FM; ++i)
#pragma unroll
        for (int j = 0; j < FN; ++j) acc[i][j] = (f32x4)0.f;

    auto STAGE = [&](int kt, u16* dA, u16* dB) {
#pragma unroll
        for (int i = 0; i < TILEM / 64; ++i)
            async_copy16(gA + (size_t)(16 * i) * kD + kt,
                         dA + (wave * (TILEM / 64) + i) * 512);
#pragma unroll
        for (int i = 0; i < TILEN / 64; ++i)
            async_copy16(gB + (size_t)(16 * i) * kD + kt,
                         dB + (wave * (TILEN / 64) + i) * 512);
    };

    const int ro = ((quad + (l15 >> 1)) & 3) * 8;   /* rotated 16B slot */
    auto COMPUTE = [&](const u16* sA, const u16* sB) {
        s16x8 af[FM], bf[FN];
#pragma unroll
        for (int fm = 0; fm < FM; ++fm)
            af[fm] = *(const s16x8*)(sA + (wr * (TILEM / 32) + fm) * 512 + l15 * 32 + ro);
#pragma unroll
        for (int fn = 0; fn < FN; ++fn)
            bf[fn] = *(const s16x8*)(sB + (wc * (TILEN / 32) + fn) * 512 + l15 * 32 + ro);
#pragma unroll
        for (int fm = 0; fm < FM; ++fm)
#pragma unroll
            for (int fn = 0; fn < FN; ++fn)
                acc[fm][fn] = __builtin_amdgcn_mfma_f32_16x16x32_bf16(
                    af[fm], bf[fn], acc[fm][fn], 0, 0, 0);
    };

    STAGE(0, As0, Bs0);
    __syncthreads();
    for (int kt = 0; kt < kD; kt += 64) {
        if (kt + 32 < kD) STAGE(kt + 32, As1, Bs1);
        COMPUTE(As0, Bs0);
        __syncthreads();
        if (kt + 64 < kD) STAGE(kt + 64, As0, Bs0);
        COMPUTE(As1, Bs1);
        __syncthreads();
    }

    /* epilogue: C/D layout col=lane&15, row=quad*4+reg */
    if constexpr (MODE == 3) {
#pragma unroll
        for (int fn = 0; fn < FN; ++fn) {
            const int sglob = n0 + wc * (TILEN / 2) + fn * 16 + l15;
            const int bb = sglob >> 11, ss = sglob & (kS - 1);
#pragma unroll
            for (int fm = 0; fm < FM; ++fm) {
                const int dglob = m0 + wr * (TILEM / 2) + fm * 16 + quad * 4;
                const float4 b4 = *(const float4*)(bias + dglob);
                const float bb4[4] = {b4.x * bscale, b4.y * bscale,
                                      b4.z * bscale, b4.w * bscale};
                const int hh = dglob >> 6, dd = dglob & 63;
                u16* base = (u16*)Cp + ((size_t)(bb * kH + hh) * 64 + dd) * kS + ss;
#pragma unroll
                for (int r = 0; r < 4; ++r)
                    base[(size_t)r * kS] = f2bf(acc[fm][fn][r] + bb4[r]);
            }
        }
    } else {
#pragma unroll
        for (int fn = 0; fn < FN; ++fn) {
            const int col = n0 + wc * (TILEN / 2) + fn * 16 + l15;
            const float bv = bias[col] * bscale;
#pragma unroll
            for (int fm = 0; fm < FM; ++fm) {
                const int row = m0 + wr * (TILEM / 2) + fm * 16 + quad * 4;
#pragma unroll
                for (int r = 0; r < 4; ++r) {
                    const float v = acc[fm][fn][r] + bv;
                    if constexpr (MODE == 0)
                        ((u16*)Cp)[(size_t)(row + r) * kD + col] = f2bf(v);
                    else
                        ((float*)Cp)[(size_t)(row + r) * kD + col] = v;
                }
            }
        }
    }
}

__global__ __launch_bounds__(256) void qkv_gemm(
        const u16* __restrict__ xq, const u16* __restrict__ xk, const u16* __restrict__ xv,
        const u16* __restrict__ wq, const u16* __restrict__ wk, const u16* __restrict__ wv,
        const float* __restrict__ bq, const float* __restrict__ bk, const float* __restrict__ bv,
        u16* __restrict__ q, u16* __restrict__ k, u16* __restrict__ vt) {
    /* ONE shared allocation for all instantiations (24 KB total) */
    __shared__ u16 AsM[2 * 128 * 32];
    __shared__ u16 BsM[2 * 64 * 32];
    /* grid (16,32,z): 512 tiles per z. T1 chunked XCD swizzle, bijective. */
    const int id = blockIdx.y * 16 + blockIdx.x;
    const int g = id & 7, mm = id >> 3;       /* mm in [0,64) */
    const int z = blockIdx.z;
    if (z == 2) {
        const int bm = mm >> 3;               /* [0,8)  */
        const int bn = g * 8 + (mm & 7);      /* [0,64) */
        gemm_bt_body<3, 128, 64>(wv, xv, bv, vt, 1.f, AsM, BsM, bm, bn);
    } else {
        const int by = g * 4 + (mm & 3);      /* [0,32) M */
        const int bx = mm >> 2;               /* [0,16) N */
        if (z == 0) gemm_bt_body<0, 128, 64>(xq, wq, bq, q, kC, AsM, BsM, bx, by);
        else        gemm_bt_body<0, 128, 64>(xk, wk, bk, k, 1.f, AsM, BsM, bx, by);
    }
}

__global__ __launch_bounds__(256) void o_gemm(const u16* __restrict__ A,
                                              const u16* __restrict__ W,
                                              const float* __restrict__ bias,
                                              float* __restrict__ C) {
    __shared__ u16 AsM[2 * 64 * 32];
    __shared__ u16 BsM[2 * 64 * 32];
    const int id = blockIdx.y * 16 + blockIdx.x;
    const int g = id & 7, mm = id >> 3;       /* mm in [0,128) */
    const int by = g * 8 + (mm & 7);          /* [0,64) M */
    const int bx = mm >> 3;                   /* [0,16) N */
    gemm_bt_body<2, 64, 64>(A, W, bias, C, 1.f, AsM, BsM, bx, by);
}

/* ---------------- MFMA flash attention (8-wave, dbuf, 1-deep pipeline) --
 * R8: software-pipeline across K/V tiles to break the per-tile serial
 * chain QK->softmax->Pwrite->PV->barrier. Scores of tile t-1 held in
 * registers (sp); iteration t issues QK(t) on the MFMA pipe, then runs
 * softmax(t-1)+PV(t-1) (VALU + MFMA on register operands) while QK(t)
 * completes. V-frags (av) read AFTER PV consumes the previous ones, and
 * before the barrier that licenses the buffer overwrite — single copy.
 * Buffer/barrier rotation identical to R2 (one __syncthreads per tile;
 * stage(t+1) at top of iter t overwrites the buffer of t-1, whose reads
 * all precede barrier #t).
 */
__global__ __launch_bounds__(512, 4) void attn_mfma(const u16* __restrict__ Qb,
                                                    const u16* __restrict__ Kb,
                                                    const u16* __restrict__ Vt,
                                                    const u64* __restrict__ prepM,
                                                    u16* __restrict__ Ob) {
    __shared__ u16 Bs2[2][8192];   /* [buf][K rows 0..63 | V rows 64..127] */
    __shared__ u16 Ps[8192];       /* 8 waves x 16 rows; holds Q in prologue */

    const int tid = threadIdx.x;
    const int wave = tid >> 6, lane = tid & 63;
    const int l15 = lane & 15, quad = lane >> 4, l7 = lane & 7;
    const int q0 = blockIdx.x * 128;
    const int b = blockIdx.y >> 4, h = blockIdx.y & 15;

    const int srow = lane >> 3;           /* 0..7 */
    const int schk = l7 ^ srow;

    /* stage Q (wave-private 16 rows) into Ps + K/V tile 0 into Bs2[0] */
    {
        const u16* g0 = Qb + ((size_t)(b * kS + q0 + 16 * wave + srow)) * kD + h * 64 + schk * 8;
        async_copy16(g0, Ps + (16 * wave) * 64);
        async_copy16(g0 + 8 * kD, Ps + (16 * wave + 8) * 64);
    }
    const u16* gK0 = Kb + ((size_t)(b * kS + 8 * wave + srow)) * kD + h * 64 + schk * 8;
    const u16* gV0 = Vt + ((size_t)((b * kH + h) * 64 + 8 * wave + srow)) * kS + schk * 8;
    async_copy16(gK0, Bs2[0] + (8 * wave) * 64);
    async_copy16(gV0, Bs2[0] + 4096 + (8 * wave) * 64);

    /* wave-uniform mask base (scalar loads); q-tile index = bx*8 + wave */
    const int wave_u = __builtin_amdgcn_readfirstlane(wave);
    const u64* mbase = prepM + (((size_t)b * 128 + blockIdx.x * 8 + wave_u) * 32) * 16;

    /* all-ones bf16 A-fragment for the denominator MFMA */
    s16x8 onesf;
#pragma unroll
    for (int i = 0; i < 8; ++i) onesf[i] = (short)0x3F80;

    f32x4 oacc[4];
#pragma unroll
    for (int i = 0; i < 4; ++i) oacc[i] = (f32x4)0.f;
    f32x4 lacc = (f32x4)0.f;

    __syncthreads();   /* Q + tile 0 landed */
    s16x8 bq0, bq1;
    bq0 = *(const s16x8*)(Ps + (16 * wave + l15) * 64 + ((0 + quad) ^ l7) * 8);
    bq1 = *(const s16x8*)(Ps + (16 * wave + l15) * 64 + ((4 + quad) ^ l7) * 8);
    u16* psrow = Ps + (16 * wave + l15) * 64;
    /* bq reads precede iter-1 P-writes to the same rows: in-wave DS order */

    f32x4 sp[4];        /* pipeline: scores of tile t-1 */
    s16x8 av[2][4];     /* pipeline: V-frags of tile t-1 */

    /* QK of one tile (MFMA pipe), into sc */
    auto QK = [&](const u16* cur, f32x4 sc[4]) {
#pragma unroll
        for (int fn = 0; fn < 4; ++fn) sc[fn] = (f32x4)0.f;
        __builtin_amdgcn_s_setprio(1);
#pragma unroll
        for (int kc = 0; kc < 2; ++kc) {
            const s16x8 bqf = kc ? bq1 : bq0;
#pragma unroll
            for (int fn = 0; fn < 4; ++fn) {
                const s16x8 ak = *(const s16x8*)(cur + (fn * 16 + l15) * 64 + ((kc * 4 + quad) ^ l7) * 8);
                sc[fn] = __builtin_amdgcn_mfma_f32_16x16x32_bf16(ak, bqf, sc[fn], 0, 0, 0);
            }
        }
        __builtin_amdgcn_s_setprio(0);
    };
    /* softmax + P-write + PV of the PREVIOUS tile (sp, av, mk) */
    auto SMPV = [&](const u64* mk) {
#pragma unroll
        for (int fn = 0; fn < 4; ++fn)
#pragma unroll
            for (int r = 0; r < 4; ++r) {
                const float p = EXP2(sp[fn][r]);
                float pm;
                asm("v_cndmask_b32 %0, 0, %1, %2" : "=v"(pm) : "v"(p), "s"(mk[fn * 4 + r]));
                sp[fn][r] = pm;
            }
#pragma unroll
        for (int fn = 0; fn < 4; ++fn) {
            uint2 o;
            o.x = cvt_pk_bf16(sp[fn][0], sp[fn][1]);
            o.y = cvt_pk_bf16(sp[fn][2], sp[fn][3]);
            const int chunk = fn * 2 + (quad >> 1);
            *(uint2*)(psrow + ((chunk ^ l7) * 8) + (quad & 1) * 4) = o;
        }
        __builtin_amdgcn_s_setprio(1);
#pragma unroll
        for (int kc = 0; kc < 2; ++kc) {
            const s16x8 bp = *(const s16x8*)(psrow + ((kc * 4 + quad) ^ l7) * 8);
            lacc = __builtin_amdgcn_mfma_f32_16x16x32_bf16(onesf, bp, lacc, 0, 0, 0);
#pragma unroll
            for (int fd = 0; fd < 4; ++fd)
                oacc[fd] = __builtin_amdgcn_mfma_f32_16x16x32_bf16(av[kc][fd], bp, oacc[fd], 0, 0, 0);
        }
        __builtin_amdgcn_s_setprio(0);
    };
    auto AV = [&](const u16* cur) {
#pragma unroll
        for (int kc = 0; kc < 2; ++kc)
#pragma unroll
            for (int fd = 0; fd < 4; ++fd)
                av[kc][fd] = *(const s16x8*)(cur + 4096 + (fd * 16 + l15) * 64 + ((kc * 4 + quad) ^ l7) * 8);
    };

    /* peeled iter 0: stage(1), QK(0)->sp, av(0); no previous tile */
    async_copy16(gK0 + (size_t)64 * kD, Bs2[1] + (8 * wave) * 64);
    async_copy16(gV0 + 64, Bs2[1] + 4096 + (8 * wave) * 64);
    QK(Bs2[0], sp);
    AV(Bs2[0]);
    __syncthreads();   /* tile 1 landed; tile-0 reads done */

    for (int t = 1; t < 32; ++t) {
        u16* cur = Bs2[t & 1];
        u16* nxt = Bs2[(t + 1) & 1];
        if (t < 31) {   /* stage(t+1) over buffer of t-1 (reads done) */
            async_copy16(gK0 + (size_t)((t + 1) * 64) * kD, nxt + (8 * wave) * 64);
            async_copy16(gV0 + (t + 1) * 64, nxt + 4096 + (8 * wave) * 64);
        }
        /* masks of tile t-1 (scalar loads, covered by QK issue) */
        const u64* mt = mbase + (t - 1) * 16;
        u64 mk[16];
#pragma unroll
        for (int i = 0; i < 16; ++i) mk[i] = mt[i];

        f32x4 sc[4];
        QK(cur, sc);       /* MFMA pipe: tile t */
        SMPV(mk);          /* VALU+MFMA: finish tile t-1 (sp, av) */
        AV(cur);           /* reload av with tile t (old ones consumed) */
#pragma unroll
        for (int fn = 0; fn < 4; ++fn) sp[fn] = sc[fn];
        __syncthreads();   /* tile t+1 landed; all reads of cur done */
    }

    /* drain tile 31 */
    {
        const u64* mt = mbase + 31 * 16;
        u64 mk[16];
#pragma unroll
        for (int i = 0; i < 16; ++i) mk[i] = mt[i];
        SMPV(mk);
    }

    /* epilogue: O^T[d][q] -> Ob[q][h*64+d]; all lacc rows equal l(q=l15) */
    const float inv = 1.f / lacc[0];
    const size_t orow = (size_t)(b * kS + q0 + 16 * wave + l15);
#pragma unroll
    for (int fd = 0; fd < 4; ++fd) {
        uint2 o;
        o.x = cvt_pk_bf16(oacc[fd][0] * inv, oacc[fd][1] * inv);
        o.y = cvt_pk_bf16(oacc[fd][2] * inv, oacc[fd][3] * inv);
        *(uint2*)(Ob + orow * kD + h * 64 + fd * 16 + quad * 4) = o;
    }
}

extern "C" void kernel_launch(void* const* d_in, const int* in_sizes, int n_in,
                              void* d_out, int out_size, void* d_ws, size_t ws_size,
                              hipStream_t stream) {
    const float* xq = (const float*)d_in[0];
    const float* xk = (const float*)d_in[1];
    const float* xv = (const float*)d_in[2];
    const int*  msk = (const int*)d_in[3];
    const float* Wq = (const float*)d_in[4];
    const float* bq = (const float*)d_in[5];
    const float* Wk = (const float*)d_in[6];
    const float* bk = (const float*)d_in[7];
    const float* Wv = (const float*)d_in[8];
    const float* bv = (const float*)d_in[9];
    const float* Wo = (const float*)d_in[10];
    const float* bo = (const float*)d_in[11];
    float* out = (float*)d_out;

    const size_t NX = (size_t)kM * kD;      /* 4,194,304 */
    const size_t NW = (size_t)kD * kD;      /* 1,048,576 */

    u64* prepM = (u64*)d_ws;                /* 1 MiB */
    u16* p = (u16*)((char*)d_ws + (1 << 20));
    u16* xqb = p; p += NX;
    u16* xkb = p; p += NX;
    u16* xvb = p; p += NX;
    u16* wqb = p; p += NW;
    u16* wkb = p; p += NW;
    u16* wvb = p; p += NW;
    u16* wob = p; p += NW;
    u16* qb  = p; p += NX;
    u16* kb  = p; p += NX;
    u16* vtb = p; p += NX;
    u16* ab  = xqb;                         /* reuse: xqb dead after qkv_gemm */

    prep<<<18432, 256, 0, stream>>>(xq, xk, xv, Wq, Wk, Wv, Wo, msk,
                                    xqb, xkb, xvb, wqb, wkb, wvb, wob, prepM);

    dim3 gq(kD / 64, kM / 128, 3);          /* (16,32,3) = 1536 blocks */
    qkv_gemm<<<gq, 256, 0, stream>>>(xqb, xkb, xvb, wqb, wkb, wvb, bq, bk, bv, qb, kb, vtb);

    dim3 ga(kS / 128, kB * kH);             /* (16,32) = 512 blocks */
    attn_mfma<<<ga, 512, 0, stream>>>(qb, kb, vtb, prepM, ab);

    dim3 go(kD / 64, kM / 64);              /* (16,64) = 1024 blocks */
    o_gemm<<<go, 256, 0, stream>>>(ab, wob, bo, out);
}

// Round 10
// 244.367 us; speedup vs baseline: 1.0096x; 1.0096x over previous
//
#include <hip/hip_runtime.h>
#include <math.h>

#define kB 2
#define kS 2048
#define kD 1024
#define kH 16
#define kM (kB * kS)     /* 4096 */

#define kC 0.180336880f   /* 0.125 * log2(e) — folded into Wq/bq at prep time */

typedef unsigned short u16;
typedef unsigned int u32;
typedef unsigned long long u64;
typedef short s16x8 __attribute__((ext_vector_type(8)));     /* bf16 MFMA frag */
typedef float f32x4 __attribute__((ext_vector_type(4)));     /* MFMA acc */

/* raw v_exp_f32 (no OCML denormal guard — inputs bounded, masked after) */
#if __has_builtin(__builtin_amdgcn_exp2f)
#define EXP2(x) __builtin_amdgcn_exp2f(x)
#else
#define EXP2(x) exp2f(x)
#endif

/* fp32 -> bf16 round-to-nearest-even (scalar) */
__device__ __forceinline__ u16 f2bf(float f) {
    u32 u = __float_as_uint(f);
    u += 0x7FFFu + ((u >> 16) & 1u);
    return (u16)(u >> 16);
}

/* pack two fp32 -> two bf16 in one u32 via v_cvt_pk_bf16_f32 (1 VALU op) */
__device__ __forceinline__ u32 cvt_pk_bf16(float lo, float hi) {
    u32 r;
    asm("v_cvt_pk_bf16_f32 %0, %1, %2" : "=v"(r) : "v"(lo), "v"(hi));
    return r;
}

typedef __attribute__((address_space(1))) void as1_void;
typedef __attribute__((address_space(3))) void as3_void;
__device__ __forceinline__ void async_copy16(const void* g, void* l) {
    __builtin_amdgcn_global_load_lds((as1_void*)(unsigned long long)g,
                                     (as3_void*)(unsigned)(unsigned long long)l,
                                     16, 0, 0);
}

/* ---------------- fused prep: bf16 converts + mask permute ---------------- */
__global__ __launch_bounds__(256) void prep(
        const float* __restrict__ xq, const float* __restrict__ xk, const float* __restrict__ xv,
        const float* __restrict__ Wq, const float* __restrict__ Wk,
        const float* __restrict__ Wv, const float* __restrict__ Wo,
        const int* __restrict__ msk,
        u16* __restrict__ xqb, u16* __restrict__ xkb, u16* __restrict__ xvb,
        u16* __restrict__ wqb, u16* __restrict__ wkb, u16* __restrict__ wvb,
        u16* __restrict__ wob, u64* __restrict__ prepM) {
    const int bid = blockIdx.x;
    const int tid = threadIdx.x;
    if (bid < 16384) {
        const float* in;
        u16* out;
        int i;
        float sc = 1.0f;
        if (bid < 12288) {
            const int z = bid >> 12;
            in = z == 0 ? xq : (z == 1 ? xk : xv);
            out = z == 0 ? xqb : (z == 1 ? xkb : xvb);
            i = (bid & 4095) * 256 + tid;
        } else {
            const int z = (bid - 12288) >> 10;
            in = z == 0 ? Wq : (z == 1 ? Wk : (z == 2 ? Wv : Wo));
            out = z == 0 ? wqb : (z == 1 ? wkb : (z == 2 ? wvb : wob));
            if (z == 0) sc = kC;            /* fold softmax scale into Wq */
            i = ((bid - 12288) & 1023) * 256 + tid;
        }
        const float4 v = ((const float4*)in)[i];
        ushort4 o;
        o.x = f2bf(v.x * sc); o.y = f2bf(v.y * sc);
        o.z = f2bf(v.z * sc); o.w = f2bf(v.w * sc);
        ((ushort4*)out)[i] = o;
    } else {
        const int wid = (bid - 16384) * 4 + (tid >> 6);  /* 0..8191 */
        const int lane = tid & 63;
        const int kt = wid & 31, qb = (wid >> 5) & 127, b = wid >> 12;
        const int q = qb * 16 + (lane & 15);
        const int kbase = kt * 64 + ((lane >> 4) << 2);
        const int* mrow = msk + ((size_t)b * kS + q) * kS;
        u64 keep = 0;
#pragma unroll
        for (int c = 0; c < 4; ++c) {
            const int4 m4 = *(const int4*)(mrow + kbase + c * 16);
            const int mv[4] = {m4.x, m4.y, m4.z, m4.w};
#pragma unroll
            for (int r = 0; r < 4; ++r) {
                const u64 bl = __ballot(mv[r] != 0);
                if (lane == c * 4 + r) keep = bl;
            }
        }
        if (lane < 16)
            prepM[(((size_t)b * 128 + qb) * 32 + kt) * 16 + lane] = keep;
    }
}

/* ---------------- bf16 GEMM: C = A[M,K] @ W[N,K]^T + bias*bscale ----------
 * TILEM x TILEN tile, BK=32 double-buffered, one barrier per K-step, shared
 * LDS from kernel scope, TILEN=64 (R7), T1 XCD swizzle (R6, GEMMs only).
 * MODE 0: bf16 out; MODE 2: f32 out; MODE 3: V^T out [(b*H+h)*64+d][s].
 */
template <int MODE, int TILEM, int TILEN>
__device__ __forceinline__ void gemm_bt_body(const u16* __restrict__ A,
                                             const u16* __restrict__ W,
                                             const float* __restrict__ bias,
                                             void* __restrict__ Cp,
                                             const float bscale,
                                             u16* __restrict__ AsM,
                                             u16* __restrict__ BsM,
                                             const int bxi, const int byi) {
    constexpr int FM = TILEM / 32;           /* m-frags per wave */
    constexpr int FN = TILEN / 32;           /* n-frags per wave */
    u16* As0 = AsM;            u16* As1 = AsM + TILEM * 32;
    u16* Bs0 = BsM;            u16* Bs1 = BsM + TILEN * 32;
    const int tid = threadIdx.x;
    const int wave = tid >> 6, lane = tid & 63;
    const int l15 = lane & 15, quad = lane >> 4;
    const int wr = wave >> 1, wc = wave & 1;
    const int m0 = (MODE == 3 ? bxi : byi) * TILEM;
    const int n0 = (MODE == 3 ? byi : bxi) * TILEN;

    /* staging: lane λ covers row λ>>2 of a 16-row block, slot λ&3; the slot
     * holds global chunk c = ((λ&3) - ((λ>>3)&3)) & 3 (rotation inverse) */
    const int srow = lane >> 2;                          /* 0..15 */
    const int schk = ((lane & 3) - ((lane >> 3) & 3)) & 3;
    const u16* gA = A + (size_t)(m0 + (TILEM / 4) * wave + srow) * kD + schk * 8;
    const u16* gB = W + (size_t)(n0 + (TILEN / 4) * wave + srow) * kD + schk * 8;

    f32x4 acc[FM][FN];
#pragma unroll
    for (int i = 0; i < FM; ++i)
#pragma unroll
        for (int j = 0; j < FN; ++j) acc[i][j] = (f32x4)0.f;

    auto STAGE = [&](int kt, u16* dA, u16* dB) {
#pragma unroll
        for (int i = 0; i < TILEM / 64; ++i)
            async_copy16(gA + (size_t)(16 * i) * kD + kt,
                         dA + (wave * (TILEM / 64) + i) * 512);
#pragma unroll
        for (int i = 0; i < TILEN / 64; ++i)
            async_copy16(gB + (size_t)(16 * i) * kD + kt,
                         dB + (wave * (TILEN / 64) + i) * 512);
    };

    const int ro = ((quad + (l15 >> 1)) & 3) * 8;   /* rotated 16B slot */
    auto COMPUTE = [&](const u16* sA, const u16* sB) {
        s16x8 af[FM], bf[FN];
#pragma unroll
        for (int fm = 0; fm < FM; ++fm)
            af[fm] = *(const s16x8*)(sA + (wr * (TILEM / 32) + fm) * 512 + l15 * 32 + ro);
#pragma unroll
        for (int fn = 0; fn < FN; ++fn)
            bf[fn] = *(const s16x8*)(sB + (wc * (TILEN / 32) + fn) * 512 + l15 * 32 + ro);
#pragma unroll
        for (int fm = 0; fm < FM; ++fm)
#pragma unroll
            for (int fn = 0; fn < FN; ++fn)
                acc[fm][fn] = __builtin_amdgcn_mfma_f32_16x16x32_bf16(
                    af[fm], bf[fn], acc[fm][fn], 0, 0, 0);
    };

    STAGE(0, As0, Bs0);
    __syncthreads();
    for (int kt = 0; kt < kD; kt += 64) {
        if (kt + 32 < kD) STAGE(kt + 32, As1, Bs1);
        COMPUTE(As0, Bs0);
        __syncthreads();
        if (kt + 64 < kD) STAGE(kt + 64, As0, Bs0);
        COMPUTE(As1, Bs1);
        __syncthreads();
    }

    /* epilogue: C/D layout col=lane&15, row=quad*4+reg */
    if constexpr (MODE == 3) {
#pragma unroll
        for (int fn = 0; fn < FN; ++fn) {
            const int sglob = n0 + wc * (TILEN / 2) + fn * 16 + l15;
            const int bb = sglob >> 11, ss = sglob & (kS - 1);
#pragma unroll
            for (int fm = 0; fm < FM; ++fm) {
                const int dglob = m0 + wr * (TILEM / 2) + fm * 16 + quad * 4;
                const float4 b4 = *(const float4*)(bias + dglob);
                const float bb4[4] = {b4.x * bscale, b4.y * bscale,
                                      b4.z * bscale, b4.w * bscale};
                const int hh = dglob >> 6, dd = dglob & 63;
                u16* base = (u16*)Cp + ((size_t)(bb * kH + hh) * 64 + dd) * kS + ss;
#pragma unroll
                for (int r = 0; r < 4; ++r)
                    base[(size_t)r * kS] = f2bf(acc[fm][fn][r] + bb4[r]);
            }
        }
    } else {
#pragma unroll
        for (int fn = 0; fn < FN; ++fn) {
            const int col = n0 + wc * (TILEN / 2) + fn * 16 + l15;
            const float bv = bias[col] * bscale;
#pragma unroll
            for (int fm = 0; fm < FM; ++fm) {
                const int row = m0 + wr * (TILEM / 2) + fm * 16 + quad * 4;
#pragma unroll
                for (int r = 0; r < 4; ++r) {
                    const float v = acc[fm][fn][r] + bv;
                    if constexpr (MODE == 0)
                        ((u16*)Cp)[(size_t)(row + r) * kD + col] = f2bf(v);
                    else
                        ((float*)Cp)[(size_t)(row + r) * kD + col] = v;
                }
            }
        }
    }
}

__global__ __launch_bounds__(256) void qkv_gemm(
        const u16* __restrict__ xq, const u16* __restrict__ xk, const u16* __restrict__ xv,
        const u16* __restrict__ wq, const u16* __restrict__ wk, const u16* __restrict__ wv,
        const float* __restrict__ bq, const float* __restrict__ bk, const float* __restrict__ bv,
        u16* __restrict__ q, u16* __restrict__ k, u16* __restrict__ vt) {
    /* ONE shared allocation for all instantiations (24 KB total) */
    __shared__ u16 AsM[2 * 128 * 32];
    __shared__ u16 BsM[2 * 64 * 32];
    /* grid (16,32,z): 512 tiles per z. T1 chunked XCD swizzle, bijective. */
    const int id = blockIdx.y * 16 + blockIdx.x;
    const int g = id & 7, mm = id >> 3;       /* mm in [0,64) */
    const int z = blockIdx.z;
    if (z == 2) {
        const int bm = mm >> 3;               /* [0,8)  */
        const int bn = g * 8 + (mm & 7);      /* [0,64) */
        gemm_bt_body<3, 128, 64>(wv, xv, bv, vt, 1.f, AsM, BsM, bm, bn);
    } else {
        const int by = g * 4 + (mm & 3);      /* [0,32) M */
        const int bx = mm >> 2;               /* [0,16) N */
        if (z == 0) gemm_bt_body<0, 128, 64>(xq, wq, bq, q, kC, AsM, BsM, bx, by);
        else        gemm_bt_body<0, 128, 64>(xk, wk, bk, k, 1.f, AsM, BsM, bx, by);
    }
}

__global__ __launch_bounds__(256) void o_gemm(const u16* __restrict__ A,
                                              const u16* __restrict__ W,
                                              const float* __restrict__ bias,
                                              float* __restrict__ C) {
    __shared__ u16 AsM[2 * 64 * 32];
    __shared__ u16 BsM[2 * 64 * 32];
    const int id = blockIdx.y * 16 + blockIdx.x;
    const int g = id & 7, mm = id >> 3;       /* mm in [0,128) */
    const int by = g * 8 + (mm & 7);          /* [0,64) M */
    const int bx = mm >> 3;                   /* [0,16) N */
    gemm_bt_body<2, 64, 64>(A, W, bias, C, 1.f, AsM, BsM, bx, by);
}

/* ---------------- MFMA flash attention (8-wave, dbuf, KVBLK=128) --------
 * R9: R2 inner math (R8 pipeline reverted — it regressed) with KVBLK
 * 64 -> 128: halves barrier count (32 -> 16 rendezvous of 8 waves),
 * doubles MFMA work and in-flight loads per sync interval.
 * LDS per buffer 32 KB: K 128x64 at 0, V^T as two 64x64 halves at
 * 8192/12288 (same XOR-swizzle per 64-col group). 2 buffers + Ps 16 KB
 * = 80 KB -> 2 blocks/CU (unchanged).
 * P processed in two 64-key halves reusing the 16 KB Ps (write-P-half
 * then PV-half; in-wave DS ordering makes the row reuse safe). Masks
 * loaded 16 u64 per half (SGPR pressure unchanged vs R2).
 */
__device__ __forceinline__ void attn_tile(
        const int t, u16* __restrict__ cur, u16* __restrict__ nxt, const bool do_stage,
        const u16* __restrict__ gK0, const u16* __restrict__ gV0,
        const u64* __restrict__ mbase,
        const s16x8 bq0, const s16x8 bq1, const s16x8 onesf,
        u16* __restrict__ psrow,
        f32x4 oacc[4], f32x4& lacc,
        const int l15, const int quad, const int l7, const int wave) {
    if (do_stage) {   /* stage tile t+1: K 16 rows/wave, V 8 rows x 2 halves */
        const int kn = (t + 1) * 128;
        async_copy16(gK0 + (size_t)kn * kD, nxt + (16 * wave) * 64);
        async_copy16(gK0 + (size_t)(kn + 8) * kD, nxt + (16 * wave + 8) * 64);
        async_copy16(gV0 + kn, nxt + 8192 + (8 * wave) * 64);
        async_copy16(gV0 + kn + 64, nxt + 12288 + (8 * wave) * 64);
    }
    const u64* mt = mbase + (size_t)t * 32;   /* 2 contiguous 64-key groups */

    /* scores^T: 8 key-fragments x 16 queries, A=K rows, B=Q rows */
    f32x4 s[8];
#pragma unroll
    for (int fn = 0; fn < 8; ++fn) s[fn] = (f32x4)0.f;
    __builtin_amdgcn_s_setprio(1);
#pragma unroll
    for (int kc = 0; kc < 2; ++kc) {
        const s16x8 bqf = kc ? bq1 : bq0;
#pragma unroll
        for (int fn = 0; fn < 8; ++fn) {
            const s16x8 ak = *(const s16x8*)(cur + (fn * 16 + l15) * 64 + ((kc * 4 + quad) ^ l7) * 8);
            s[fn] = __builtin_amdgcn_mfma_f32_16x16x32_bf16(ak, bqf, s[fn], 0, 0, 0);
        }
    }
    __builtin_amdgcn_s_setprio(0);

    /* two 64-key halves: softmax + P-write + PV (Ps reused per half) */
#pragma unroll
    for (int h = 0; h < 2; ++h) {
        u64 mk[16];
#pragma unroll
        for (int i = 0; i < 16; ++i) mk[i] = mt[h * 16 + i];
#pragma unroll
        for (int f2 = 0; f2 < 4; ++f2)
#pragma unroll
            for (int r = 0; r < 4; ++r) {
                const float p = EXP2(s[h * 4 + f2][r]);
                float pm;
                asm("v_cndmask_b32 %0, 0, %1, %2" : "=v"(pm) : "v"(p), "s"(mk[f2 * 4 + r]));
                s[h * 4 + f2][r] = pm;
            }
#pragma unroll
        for (int f2 = 0; f2 < 4; ++f2) {
            uint2 o;
            o.x = cvt_pk_bf16(s[h * 4 + f2][0], s[h * 4 + f2][1]);
            o.y = cvt_pk_bf16(s[h * 4 + f2][2], s[h * 4 + f2][3]);
            const int chunk = f2 * 2 + (quad >> 1);
            *(uint2*)(psrow + ((chunk ^ l7) * 8) + (quad & 1) * 4) = o;
        }
        const u16* Vh = cur + 8192 + h * 4096;
        __builtin_amdgcn_s_setprio(1);
#pragma unroll
        for (int kc = 0; kc < 2; ++kc) {
            const s16x8 bp = *(const s16x8*)(psrow + ((kc * 4 + quad) ^ l7) * 8);
            lacc = __builtin_amdgcn_mfma_f32_16x16x32_bf16(onesf, bp, lacc, 0, 0, 0);
#pragma unroll
            for (int fd = 0; fd < 4; ++fd) {
                const s16x8 av = *(const s16x8*)(Vh + (fd * 16 + l15) * 64 + ((kc * 4 + quad) ^ l7) * 8);
                oacc[fd] = __builtin_amdgcn_mfma_f32_16x16x32_bf16(av, bp, oacc[fd], 0, 0, 0);
            }
        }
        __builtin_amdgcn_s_setprio(0);
    }
    __syncthreads();   /* tile t+1 landed; all waves done with cur */
}

__global__ __launch_bounds__(512) void attn_mfma(const u16* __restrict__ Qb,
                                                 const u16* __restrict__ Kb,
                                                 const u16* __restrict__ Vt,
                                                 const u64* __restrict__ prepM,
                                                 u16* __restrict__ Ob) {
    __shared__ u16 Bs2[2][16384];  /* [buf][K 128x64 | V half0 | V half1] */
    __shared__ u16 Ps[8192];       /* 8 waves x 16 rows; holds Q in prologue */

    const int tid = threadIdx.x;
    const int wave = tid >> 6, lane = tid & 63;
    const int l15 = lane & 15, quad = lane >> 4, l7 = lane & 7;
    const int q0 = blockIdx.x * 128;
    const int b = blockIdx.y >> 4, h = blockIdx.y & 15;

    const int srow = lane >> 3;           /* 0..7 */
    const int schk = l7 ^ srow;

    /* stage Q (wave-private 16 rows) into Ps + K/V tile 0 into Bs2[0] */
    {
        const u16* g0 = Qb + ((size_t)(b * kS + q0 + 16 * wave + srow)) * kD + h * 64 + schk * 8;
        async_copy16(g0, Ps + (16 * wave) * 64);
        async_copy16(g0 + 8 * kD, Ps + (16 * wave + 8) * 64);
    }
    const u16* gK0 = Kb + ((size_t)(b * kS + 16 * wave + srow)) * kD + h * 64 + schk * 8;
    const u16* gV0 = Vt + ((size_t)((b * kH + h) * 64 + 8 * wave + srow)) * kS + schk * 8;
    async_copy16(gK0, Bs2[0] + (16 * wave) * 64);
    async_copy16(gK0 + (size_t)8 * kD, Bs2[0] + (16 * wave + 8) * 64);
    async_copy16(gV0, Bs2[0] + 8192 + (8 * wave) * 64);
    async_copy16(gV0 + 64, Bs2[0] + 12288 + (8 * wave) * 64);

    /* wave-uniform mask base (scalar loads); q-tile index = bx*8 + wave */
    const int wave_u = __builtin_amdgcn_readfirstlane(wave);
    const u64* mbase = prepM + (((size_t)b * 128 + blockIdx.x * 8 + wave_u) * 32) * 16;

    /* all-ones bf16 A-fragment for the denominator MFMA */
    s16x8 onesf;
#pragma unroll
    for (int i = 0; i < 8; ++i) onesf[i] = (short)0x3F80;

    f32x4 oacc[4];
#pragma unroll
    for (int i = 0; i < 4; ++i) oacc[i] = (f32x4)0.f;
    f32x4 lacc = (f32x4)0.f;

    __syncthreads();   /* Q + tile 0 landed */
    s16x8 bq0, bq1;
    bq0 = *(const s16x8*)(Ps + (16 * wave + l15) * 64 + ((0 + quad) ^ l7) * 8);
    bq1 = *(const s16x8*)(Ps + (16 * wave + l15) * 64 + ((4 + quad) ^ l7) * 8);
    u16* psrow = Ps + (16 * wave + l15) * 64;
    /* bq reads precede tile-0 P-writes to the same rows: in-wave DS order */

    for (int ti = 0; ti < 16; ti += 2) {
        attn_tile(ti, Bs2[0], Bs2[1], true,
                  gK0, gV0, mbase, bq0, bq1, onesf, psrow, oacc, lacc,
                  l15, quad, l7, wave);
        attn_tile(ti + 1, Bs2[1], Bs2[0], ti + 2 < 16,
                  gK0, gV0, mbase, bq0, bq1, onesf, psrow, oacc, lacc,
                  l15, quad, l7, wave);
    }

    /* epilogue: O^T[d][q] -> Ob[q][h*64+d]; all lacc rows equal l(q=l15) */
    const float inv = 1.f / lacc[0];
    const size_t orow = (size_t)(b * kS + q0 + 16 * wave + l15);
#pragma unroll
    for (int fd = 0; fd < 4; ++fd) {
        uint2 o;
        o.x = cvt_pk_bf16(oacc[fd][0] * inv, oacc[fd][1] * inv);
        o.y = cvt_pk_bf16(oacc[fd][2] * inv, oacc[fd][3] * inv);
        *(uint2*)(Ob + orow * kD + h * 64 + fd * 16 + quad * 4) = o;
    }
}

extern "C" void kernel_launch(void* const* d_in, const int* in_sizes, int n_in,
                              void* d_out, int out_size, void* d_ws, size_t ws_size,
                              hipStream_t stream) {
    const float* xq = (const float*)d_in[0];
    const float* xk = (const float*)d_in[1];
    const float* xv = (const float*)d_in[2];
    const int*  msk = (const int*)d_in[3];
    const float* Wq = (const float*)d_in[4];
    const float* bq = (const float*)d_in[5];
    const float* Wk = (const float*)d_in[6];
    const float* bk = (const float*)d_in[7];
    const float* Wv = (const float*)d_in[8];
    const float* bv = (const float*)d_in[9];
    const float* Wo = (const float*)d_in[10];
    const float* bo = (const float*)d_in[11];
    float* out = (float*)d_out;

    const size_t NX = (size_t)kM * kD;      /* 4,194,304 */
    const size_t NW = (size_t)kD * kD;      /* 1,048,576 */

    u64* prepM = (u64*)d_ws;                /* 1 MiB */
    u16* p = (u16*)((char*)d_ws + (1 << 20));
    u16* xqb = p; p += NX;
    u16* xkb = p; p += NX;
    u16* xvb = p; p += NX;
    u16* wqb = p; p += NW;
    u16* wkb = p; p += NW;
    u16* wvb = p; p += NW;
    u16* wob = p; p += NW;
    u16* qb  = p; p += NX;
    u16* kb  = p; p += NX;
    u16* vtb = p; p += NX;
    u16* ab  = xqb;                         /* reuse: xqb dead after qkv_gemm */

    prep<<<18432, 256, 0, stream>>>(xq, xk, xv, Wq, Wk, Wv, Wo, msk,
                                    xqb, xkb, xvb, wqb, wkb, wvb, wob, prepM);

    dim3 gq(kD / 64, kM / 128, 3);          /* (16,32,3) = 1536 blocks */
    qkv_gemm<<<gq, 256, 0, stream>>>(xqb, xkb, xvb, wqb, wkb, wvb, bq, bk, bv, qb, kb, vtb);

    dim3 ga(kS / 128, kB * kH);             /* (16,32) = 512 blocks */
    attn_mfma<<<ga, 512, 0, stream>>>(qb, kb, vtb, prepM, ab);

    dim3 go(kD / 64, kM / 64);              /* (16,64) = 1024 blocks */
    o_gemm<<<go, 256, 0, stream>>>(ab, wob, bo, out);
}